// Round 22
// baseline (167.183 us; speedup 1.0000x reference)
//
#include <hip/hip_runtime.h>

#define N_NODES 10000
#define N_EDGES 160000
#define E_TOT   170000   // + self loops
#define H1      8
#define C1      120
#define F1      960      // H1*C1
#define BSTRIDE 64       // bucket slots per node (max in-degree ~45 << 64)

typedef _Float16 h2 __attribute__((ext_vector_type(2)));
typedef _Float16 f16x8 __attribute__((ext_vector_type(8)));
typedef float f32x4 __attribute__((ext_vector_type(4)));
typedef float f32x16 __attribute__((ext_vector_type(16)));
union H2U { unsigned u; h2 h; };
union AU  { uint4 u; f16x8 h; };

#if defined(__has_builtin)
#if __has_builtin(__builtin_amdgcn_fdot2)
#define FDOT2(a,b,c) __builtin_amdgcn_fdot2((a),(b),(c),false)
#endif
#endif
#ifndef FDOT2
#define FDOT2(a,b,c) ((float)(a)[0]*(float)(b)[0] + (float)(a)[1]*(float)(b)[1] + (c))
#endif

__device__ __forceinline__ float lrelu(float v) { return fmaxf(v, 0.2f * v); }
__device__ __forceinline__ unsigned packh2(float a, float b) {
    H2U u; u.h = (h2){(_Float16)a, (_Float16)b}; return u.u;
}
__device__ __forceinline__ h2 toh2(unsigned v) { H2U u; u.u = v; return u.h; }

// ---------------- aux: zero cnt + agg-phase tables ----------------
// blocks 0..39: cnt[i] = 0
// blocks 40..43: WAh/PBh (orig-order f16 Wl cols, {b1l,bias1}) + W2P pair tables
__global__ __launch_bounds__(256) void aux(
        const float* __restrict__ W1l,
        const float* __restrict__ b1l, const float* __restrict__ bias1,
        const float* __restrict__ W2l, const float* __restrict__ W2r,
        uint2* __restrict__ WAh, unsigned* __restrict__ PBh,
        uint4* __restrict__ W2P, int* __restrict__ cnt) {
    int b = blockIdx.x, t = threadIdx.x;
    if (b < 40) {
        int i = b * 256 + t;
        if (i < N_NODES) cnt[i] = 0;
        return;
    }
    int bb = b - 40;
    if (t < 240) {
        int rc = bb * 240 + t;
        float wl0 = W1l[rc], wl1 = W1l[F1+rc], wl2 = W1l[2*F1+rc], wl3 = W1l[3*F1+rc];
        WAh[rc] = make_uint2(packh2(wl0, wl1), packh2(wl2, wl3));
        PBh[rc] = packh2(b1l[rc], bias1[rc]);
    }
    if (t < 120) {
        int i = bb * 120 + t;          // pair index: h = i/60, u = i%60
        int h = i / 60, u = i - h * 60;
        int c0 = h * C1 + u, c1 = c0 + 60;
        const float4 wl0 = ((const float4*)W2l)[c0], wl1 = ((const float4*)W2l)[c1];
        const float4 wr0 = ((const float4*)W2r)[c0], wr1 = ((const float4*)W2r)[c1];
        W2P[i*2]   = make_uint4(packh2(wl0.x, wl1.x), packh2(wl0.y, wl1.y),
                                packh2(wl0.z, wl1.z), packh2(wl0.w, wl1.w));
        W2P[i*2+1] = make_uint4(packh2(wr0.x, wr1.x), packh2(wr0.y, wr1.y),
                                packh2(wr0.z, wr1.z), packh2(wr0.w, wr1.w));
    }
}

// ---------------- layer-1 logits: self-contained (table build + MFMA) ----------------
// 512-thread blocks (8 waves, 256 edges; 32 edges/wave, 32x32x16 MFMA).
// Each block builds IN-LDS: the |0.4*att|-folded positives-first weight table
// (rank loop, L1-resident), P (x0.6 linear coefs), Bh. Ls/Lr computed inline
// per edge from x + P (no global Ls/Lr). Bucket fill fused; e1 written in
// BUCKET order (slot from eposL) so fused_agg1 reads contiguously.

__global__ __launch_bounds__(512) void logits_all(
        const int* __restrict__ ei, const float* __restrict__ x,
        const float* __restrict__ W1l, const float* __restrict__ W1r,
        const float* __restrict__ b1l, const float* __restrict__ b1r,
        const float* __restrict__ att1,
        int* __restrict__ cnt, int* __restrict__ slist,
        float* __restrict__ e1) {
    __shared__ uint4 BpL[2048];   // 32 KB weight table (32x32 tiles, sorted)
    __shared__ float PsL[72];     // 0.6-scaled linear coefs
    __shared__ int   BhL[8];      // positives per head
    __shared__ int   eposL[256];  // bucket slot per block-local edge
    int tid = threadIdx.x;

    // A0: bucket fill (independent; completes by the final barrier)
    {
        int lidx = tid & 255;
        int ef = blockIdx.x * 256 + lidx;
        if (tid < 256 && ef < E_TOT) {
            int s, d;
            if (ef < N_EDGES) { s = ei[ef]; d = ei[N_EDGES + ef]; }
            else { s = ef - N_EDGES; d = s; }
            int pos = atomicAdd(&cnt[d], 1);
            int slot = d * BSTRIDE + pos;
            slist[slot] = s;
            eposL[lidx] = slot;
        }
    }
    // A1: zero the table
#pragma unroll
    for (int i = 0; i < 4; ++i) BpL[tid + i*512] = make_uint4(0u,0u,0u,0u);
    __syncthreads();

    // A2: build tables. threads 0..479: 2 channels each (rank loop + fold+pack);
    //     threads 480..511: P outputs (o = t-480, +32, +64).
    if (tid < 480) {
#pragma unroll
        for (int k = 0; k < 2; ++k) {
            int rc = tid * 2 + k;
            int h = rc / C1, u = rc - h * C1;
            float a = att1[rc];
            int cntPos = 0, rankB = 0;
            for (int v = 0; v < C1; ++v) {
                bool pos = att1[h*C1 + v] > 0.f;
                cntPos += pos ? 1 : 0;
                rankB  += (v < u && pos) ? 1 : 0;
            }
            int newu = (a > 0.f) ? rankB : (cntPos + (u - rankB));
            float sc = fabsf(0.4f * a);
            float wl0 = W1l[rc], wl1 = W1l[F1+rc], wl2 = W1l[2*F1+rc], wl3 = W1l[3*F1+rc];
            float wr0 = W1r[rc], wr1 = W1r[F1+rc], wr2 = W1r[2*F1+rc], wr3 = W1r[3*F1+rc];
            float bc = b1l[rc] + b1r[rc];
            int pc2 = h * 128 + newu;
            int ct = pc2 >> 5, cl2 = pc2 & 31;
            BpL[ct*64 + cl2] = make_uint4(packh2(sc*wl0, sc*wl1), packh2(sc*wl2, sc*wl3),
                                          packh2(sc*wr0, sc*wr1), packh2(sc*wr2, sc*wr3));
            BpL[ct*64 + 32 + cl2] = make_uint4(packh2(sc*bc, 0.f), 0u, 0u, 0u);
            if (u == 0) BhL[h] = cntPos;
        }
    } else {
        for (int o = tid - 480; o < 72; o += 32) {
            int h = o / 9, j = o % 9;
            float acc = 0.f;
            for (int u = 0; u < C1; ++u) {
                int c = h * C1 + u;
                float a = att1[c];
                float w;
                if (j < 4)      w = W1l[j * F1 + c];
                else if (j < 8) w = W1r[(j - 4) * F1 + c];
                else            w = b1l[c] + b1r[c];
                acc = fmaf(a, w, acc);
            }
            PsL[o] = 0.6f * acc;
        }
    }
    __syncthreads();

    // Phase B: MFMA logits (32 edges/wave)
    int ebase = blockIdx.x * 256 + (tid >> 6) * 32;
    if (ebase >= E_TOT) return;
    int lane = tid & 63;
    int ecol = lane & 31, g2 = lane >> 5;

    int s0 = 0, d0 = 0;
    float4 xs = make_float4(0.f,0.f,0.f,0.f), xd = xs;
    AU zu;
    if (g2 == 0) {
        int er = ebase + ecol;
        if (er >= E_TOT) er = E_TOT - 1;
        if (er < N_EDGES) { s0 = ei[er]; d0 = ei[N_EDGES + er]; }
        else { s0 = er - N_EDGES; d0 = s0; }
        xs = ((const float4*)x)[s0];
        xd = ((const float4*)x)[d0];
        zu.u = make_uint4(packh2(xs.x, xs.y), packh2(xs.z, xs.w),
                          packh2(xd.x, xd.y), packh2(xd.z, xd.w));
    } else {
        zu.u = make_uint4(0x00003C00u, 0u, 0u, 0u);   // k8 = 1.0 (bias row)
    }
    // broadcast this edge's x to both lane halves (for inline Ls/Lr)
    float xsx = __shfl(xs.x, ecol, 64), xsy = __shfl(xs.y, ecol, 64);
    float xsz = __shfl(xs.z, ecol, 64), xsw = __shfl(xs.w, ecol, 64);
    float xdx = __shfl(xd.x, ecol, 64), xdy = __shfl(xd.y, ecol, 64);
    float xdz = __shfl(xd.z, ecol, 64), xdw = __shfl(xd.w, ecol, 64);
    // inline linear part for this lane's 4 heads (hbase = 4*g2)
    float lin0, lin1, lin2, lin3;
    {
        int hb = 4 * g2;
        const float* p0 = PsL + (hb+0)*9;
        const float* p1 = PsL + (hb+1)*9;
        const float* p2 = PsL + (hb+2)*9;
        const float* p3 = PsL + (hb+3)*9;
        lin0 = xsx*p0[0]+xsy*p0[1]+xsz*p0[2]+xsw*p0[3] + xdx*p0[4]+xdy*p0[5]+xdz*p0[6]+xdw*p0[7] + p0[8];
        lin1 = xsx*p1[0]+xsy*p1[1]+xsz*p1[2]+xsw*p1[3] + xdx*p1[4]+xdy*p1[5]+xdz*p1[6]+xdw*p1[7] + p1[8];
        lin2 = xsx*p2[0]+xsy*p2[1]+xsz*p2[2]+xsw*p2[3] + xdx*p2[4]+xdy*p2[5]+xdz*p2[6]+xdw*p2[7] + p2[8];
        lin3 = xsx*p3[0]+xsy*p3[1]+xsz*p3[2]+xsw*p3[3] + xdx*p3[4]+xdy*p3[5]+xdz*p3[6]+xdw*p3[7] + p3[8];
    }

    float kk0 = 0.f, kk1 = 0.f, kk2 = 0.f, kk3 = 0.f;
#pragma unroll
    for (int h = 0; h < H1; ++h) {
        int bh = BhL[h];
        float aa = 0.f;
#pragma unroll
        for (int tt = 0; tt < 4; ++tt) {
            int ct = h * 4 + tt;
            AU wu; wu.u = BpL[ct*64 + lane];
            f32x16 z = {0.f,0.f,0.f,0.f,0.f,0.f,0.f,0.f,0.f,0.f,0.f,0.f,0.f,0.f,0.f,0.f};
            f32x16 dd = __builtin_amdgcn_mfma_f32_32x32x16_f16(wu.h, zu.h, z, 0, 0, 0);
#pragma unroll
            for (int r = 0; r < 16; ++r) {
                int row = (r & 3) + 8 * (r >> 2) + 4 * g2;
                float sel = (tt*32 + row < bh) ? 1.f : -1.f;
                aa = fmaf(sel, fabsf(dd[r]), aa);
            }
        }
        aa += __shfl_xor(aa, 32, 64);   // combine complementary row halves
        bool pk = ((h >> 2) == g2);
        if ((h & 3) == 0)      kk0 = pk ? aa : kk0;
        else if ((h & 3) == 1) kk1 = pk ? aa : kk1;
        else if ((h & 3) == 2) kk2 = pk ? aa : kk2;
        else                   kk3 = pk ? aa : kk3;
    }

    // writeout to bucket slot (lane (ecol,g2) writes heads 4*g2..4*g2+3)
    {
        int e0 = ebase + ecol;
        if (e0 < E_TOT) {
            int slot = eposL[(tid >> 6) * 32 + ecol];
            float4 o = make_float4(__expf(lin0 + kk0), __expf(lin1 + kk1),
                                   __expf(lin2 + kk2), __expf(lin3 + kk3));
            *(float4*)(e1 + (size_t)slot*8 + 4*g2) = o;
        }
    }
}

// ---------------- layer-1 agg + f16 expand + relu + layer-2 transform ----------------
// 16 lanes per node; bucket CSR; e1 read CONTIGUOUSLY (bucket order)

#define AGG(hi, wv) { float W_ = (wv); ssum[hi] += W_; ag[hi].x += W_*xv.x; ag[hi].y += W_*xv.y; ag[hi].z += W_*xv.z; ag[hi].w += W_*xv.w; }

__global__ __launch_bounds__(256) void fused_agg1(
        const int* __restrict__ cnt, const int* __restrict__ slist,
        const float* __restrict__ e1, const float* __restrict__ x,
        const uint2* __restrict__ WAh, const unsigned* __restrict__ PBh,
        const uint4* __restrict__ W2P,
        const float* __restrict__ b2l, const float* __restrict__ b2r,
        float* __restrict__ xl2, float* __restrict__ xr2) {
    int tid = threadIdx.x;
    int node = blockIdx.x * 16 + (tid >> 4);
    int l = tid & 15;
    int beg = node * BSTRIDE, end = beg + cnt[node];

    float ssum[H1]; float4 ag[H1];
#pragma unroll
    for (int h = 0; h < H1; ++h) { ssum[h] = 0.f; ag[h] = make_float4(0.f,0.f,0.f,0.f); }

    for (int i = beg + l; i < end; i += 16) {
        const float4* p = (const float4*)(e1 + (size_t)i * 8);
        float4 wa = p[0], wb = p[1];
        float4 xv = ((const float4*)x)[slist[i]];
        AGG(0, wa.x) AGG(1, wa.y) AGG(2, wa.z) AGG(3, wa.w)
        AGG(4, wb.x) AGG(5, wb.y) AGG(6, wb.z) AGG(7, wb.w)
    }
#pragma unroll
    for (int off = 8; off; off >>= 1) {
#pragma unroll
        for (int h = 0; h < H1; ++h) {
            ssum[h] += __shfl_xor(ssum[h], off, 64);
            ag[h].x += __shfl_xor(ag[h].x, off, 64);
            ag[h].y += __shfl_xor(ag[h].y, off, 64);
            ag[h].z += __shfl_xor(ag[h].z, off, 64);
            ag[h].w += __shfl_xor(ag[h].w, off, 64);
        }
    }
    unsigned agA[H1], agB[H1], sg[H1];
#pragma unroll
    for (int h = 0; h < H1; ++h) {
        float inv = 1.f / (ssum[h] + 1e-16f);
        agA[h] = packh2(ag[h].x * inv, ag[h].y * inv);
        agB[h] = packh2(ag[h].z * inv, ag[h].w * inv);
        sg[h]  = packh2(ssum[h] * inv, 1.f);
    }

    float al0=0, al1=0, al2=0, al3=0, ar0=0, ar1=0, ar2=0, ar3=0;
#pragma unroll
    for (int h = 0; h < H1; ++h) {
        h2 ga = toh2(agA[h]), gb = toh2(agB[h]), gs = toh2(sg[h]);
#pragma unroll
        for (int j = 0; j < 4; ++j) {
            int u = l + 16*j;
            if (u < 60) {
                int c0 = h*C1 + u;
                uint2 wa0 = WAh[c0];      unsigned pb0 = PBh[c0];
                uint2 wa1 = WAh[c0 + 60]; unsigned pb1 = PBh[c0 + 60];
                float f0 = FDOT2(gs, toh2(pb0), 0.f);
                f0 = FDOT2(ga, toh2(wa0.x), f0);
                f0 = FDOT2(gb, toh2(wa0.y), f0);
                f0 = fmaxf(f0, 0.f);
                float f1 = FDOT2(gs, toh2(pb1), 0.f);
                f1 = FDOT2(ga, toh2(wa1.x), f1);
                f1 = FDOT2(gb, toh2(wa1.y), f1);
                f1 = fmaxf(f1, 0.f);
                h2 hp = toh2(packh2(f0, f1));
                int pi = (h*60 + u) * 2;
                uint4 wA = W2P[pi], wB = W2P[pi + 1];
                al0 = FDOT2(hp, toh2(wA.x), al0); al1 = FDOT2(hp, toh2(wA.y), al1);
                al2 = FDOT2(hp, toh2(wA.z), al2); al3 = FDOT2(hp, toh2(wA.w), al3);
                ar0 = FDOT2(hp, toh2(wB.x), ar0); ar1 = FDOT2(hp, toh2(wB.y), ar1);
                ar2 = FDOT2(hp, toh2(wB.z), ar2); ar3 = FDOT2(hp, toh2(wB.w), ar3);
            }
        }
    }
#pragma unroll
    for (int off = 8; off; off >>= 1) {
        al0 += __shfl_xor(al0, off, 64); al1 += __shfl_xor(al1, off, 64);
        al2 += __shfl_xor(al2, off, 64); al3 += __shfl_xor(al3, off, 64);
        ar0 += __shfl_xor(ar0, off, 64); ar1 += __shfl_xor(ar1, off, 64);
        ar2 += __shfl_xor(ar2, off, 64); ar3 += __shfl_xor(ar3, off, 64);
    }
    if (l == 0) {
        ((float4*)xl2)[node] = make_float4(al0 + b2l[0], al1 + b2l[1], al2 + b2l[2], al3 + b2l[3]);
        ((float4*)xr2)[node] = make_float4(ar0 + b2r[0], ar1 + b2r[1], ar2 + b2r[2], ar3 + b2r[3]);
    }
}

// ---------------- layer-2 fused attention ----------------

__global__ __launch_bounds__(256) void attn2(
        const int* __restrict__ cnt, const int* __restrict__ slist,
        const float* __restrict__ xl2, const float* __restrict__ xr2,
        const float* __restrict__ att2, const float* __restrict__ bias2,
        float* __restrict__ out) {
    int tid = threadIdx.x;
    int node = blockIdx.x * 16 + (tid >> 4);
    int l = tid & 15;
    int beg = node * BSTRIDE, end = beg + cnt[node];
    float4 xr = ((const float4*)xr2)[node];
    float a0 = att2[0], a1 = att2[1], a2 = att2[2], a3 = att2[3];

    float ssum = 0.f;
    float4 acc = make_float4(0.f, 0.f, 0.f, 0.f);
    for (int i = beg + l; i < end; i += 16) {
        float4 v = ((const float4*)xl2)[slist[i]];
        float lg = a0*lrelu(v.x + xr.x) + a1*lrelu(v.y + xr.y)
                 + a2*lrelu(v.z + xr.z) + a3*lrelu(v.w + xr.w);
        float w = __expf(lg);
        ssum += w;
        acc.x += w*v.x; acc.y += w*v.y; acc.z += w*v.z; acc.w += w*v.w;
    }
#pragma unroll
    for (int off = 8; off; off >>= 1) {
        ssum  += __shfl_xor(ssum,  off, 64);
        acc.x += __shfl_xor(acc.x, off, 64);
        acc.y += __shfl_xor(acc.y, off, 64);
        acc.z += __shfl_xor(acc.z, off, 64);
        acc.w += __shfl_xor(acc.w, off, 64);
    }
    if (l == 0) {
        float inv = 1.f / (ssum + 1e-16f);
        ((float4*)out)[node] = make_float4(acc.x*inv + bias2[0], acc.y*inv + bias2[1],
                                           acc.z*inv + bias2[2], acc.w*inv + bias2[3]);
    }
}

extern "C" void kernel_launch(void* const* d_in, const int* in_sizes, int n_in,
                              void* d_out, int out_size, void* d_ws, size_t ws_size,
                              hipStream_t stream) {
    const float* x     = (const float*)d_in[0];
    const int*   ei    = (const int*)  d_in[1];
    const float* W1l   = (const float*)d_in[2];
    const float* W1r   = (const float*)d_in[3];
    const float* b1l   = (const float*)d_in[4];
    const float* b1r   = (const float*)d_in[5];
    const float* att1  = (const float*)d_in[6];
    const float* bias1 = (const float*)d_in[7];
    const float* W2l   = (const float*)d_in[8];
    const float* W2r   = (const float*)d_in[9];
    const float* b2l   = (const float*)d_in[10];
    const float* b2r   = (const float*)d_in[11];
    const float* att2  = (const float*)d_in[12];
    const float* bias2 = (const float*)d_in[13];
    float* out = (float*)d_out;

    // workspace carve-up (segments 16B-aligned)
    float* e1   = (float*)d_ws;                        // N_NODES*BSTRIDE*8 = 5,120,000 f (BUCKET order)
    float* xl2  = e1 + (size_t)N_NODES * BSTRIDE * 8;  // 40,000
    float* xr2  = xl2 + 40000;                         // 40,000
    unsigned* WAhu = (unsigned*)(xr2 + 40000);         // 1,920 (uint2[960])
    unsigned* W2Pu = WAhu + 1920;                      // 7,680 (uint4[1920])
    unsigned* PBhu = W2Pu + 7680;                      // 960
    int* cnt    = (int*)(PBhu + 960);                  // 10,000
    int* slist  = cnt + 10000;                         // N_NODES*BSTRIDE = 640,000

    const int B = 256;

    aux<<<44, B, 0, stream>>>(W1l, b1l, bias1, W2l, W2r,
                              (uint2*)WAhu, PBhu, (uint4*)W2Pu, cnt);

    logits_all<<<(E_TOT + 255) / 256, 512, 0, stream>>>(
        ei, x, W1l, W1r, b1l, b1r, att1, cnt, slist, e1);
    fused_agg1<<<N_NODES / 16, B, 0, stream>>>(
        cnt, slist, e1, x, (const uint2*)WAhu, PBhu, (const uint4*)W2Pu,
        b2l, b2r, xl2, xr2);
    attn2<<<N_NODES / 16, B, 0, stream>>>(cnt, slist, xl2, xr2, att2, bias2, out);
}

// Round 23
// 66.199 us; speedup vs baseline: 2.5255x; 2.5255x over previous
//
#include <hip/hip_runtime.h>

#define N_NODES 10000
#define N_EDGES 160000
#define E_TOT   170000   // + self loops
#define H1      8
#define C1      120
#define F1      960      // H1*C1
#define BSTRIDE 64       // bucket slots per node (max in-degree ~45 << 64)

typedef _Float16 h2 __attribute__((ext_vector_type(2)));
typedef _Float16 f16x8 __attribute__((ext_vector_type(8)));
typedef float f32x4 __attribute__((ext_vector_type(4)));
typedef float f32x16 __attribute__((ext_vector_type(16)));
union H2U { unsigned u; h2 h; };
union AU  { uint4 u; f16x8 h; };

#if defined(__has_builtin)
#if __has_builtin(__builtin_amdgcn_fdot2)
#define FDOT2(a,b,c) __builtin_amdgcn_fdot2((a),(b),(c),false)
#endif
#endif
#ifndef FDOT2
#define FDOT2(a,b,c) ((float)(a)[0]*(float)(b)[0] + (float)(a)[1]*(float)(b)[1] + (c))
#endif

__device__ __forceinline__ float lrelu(float v) { return fmaxf(v, 0.2f * v); }
__device__ __forceinline__ unsigned packh2(float a, float b) {
    H2U u; u.h = (h2){(_Float16)a, (_Float16)b}; return u.u;
}
__device__ __forceinline__ h2 toh2(unsigned v) { H2U u; u.u = v; return u.h; }

// ---------------- fused prep ----------------
// blocks 0..3: zero own Bp range; t<240: |0.4*att|-folded sorted weight table
//   in 32x32-tile layout (pc2 = h*128+newu, ct = pc2>>5, cl = pc2&31);
//   Bh[h] = #pos; WAh/PBh (orig order); W2P (t<120).
// blocks 4..43: Ps 3-way-parallel; 250 nodes each: xh pack, Ls, Lr.
// blocks 44..83: zero cnt.
__global__ __launch_bounds__(256) void prep(
        const float* __restrict__ x,
        const float* __restrict__ W1l, const float* __restrict__ W1r,
        const float* __restrict__ b1l, const float* __restrict__ b1r,
        const float* __restrict__ att1, const float* __restrict__ bias1,
        const float* __restrict__ W2l, const float* __restrict__ W2r,
        uint4* __restrict__ BpH, int* __restrict__ Bh,
        uint2* __restrict__ WAh, unsigned* __restrict__ PBh,
        uint4* __restrict__ W2P,
        uint2* __restrict__ xh, float* __restrict__ Ls, float* __restrict__ Lr,
        int* __restrict__ cnt) {
    int b = blockIdx.x, t = threadIdx.x;
    if (b >= 44) {
        int i = (b - 44) * 256 + t;
        if (i < N_NODES) cnt[i] = 0;
        return;
    }
    if (b < 4) {
        BpH[b*512 + t]       = make_uint4(0u,0u,0u,0u);
        BpH[b*512 + 256 + t] = make_uint4(0u,0u,0u,0u);
        __syncthreads();
        if (t < 240) {
            int rc = b * 240 + t;
            int h = rc / C1, u = rc - h * C1;
            float a = att1[rc];
            int cntPos = 0, rankB = 0;
            for (int v = 0; v < C1; ++v) {
                bool pos = att1[h*C1 + v] > 0.f;
                cntPos += pos ? 1 : 0;
                rankB  += (v < u && pos) ? 1 : 0;
            }
            int newu = (a > 0.f) ? rankB : (cntPos + (u - rankB));
            float sc = fabsf(0.4f * a);
            float wl0 = W1l[rc], wl1 = W1l[F1+rc], wl2 = W1l[2*F1+rc], wl3 = W1l[3*F1+rc];
            float wr0 = W1r[rc], wr1 = W1r[F1+rc], wr2 = W1r[2*F1+rc], wr3 = W1r[3*F1+rc];
            float bc = b1l[rc] + b1r[rc];
            int pc2 = h * 128 + newu;
            int ct = pc2 >> 5, cl2 = pc2 & 31;    // 32-channel tiles
            BpH[ct*64 + cl2] = make_uint4(packh2(sc*wl0, sc*wl1), packh2(sc*wl2, sc*wl3),
                                          packh2(sc*wr0, sc*wr1), packh2(sc*wr2, sc*wr3));
            BpH[ct*64 + 32 + cl2] = make_uint4(packh2(sc*bc, 0.f), 0u, 0u, 0u);
            if (u == 0) Bh[h] = cntPos;
            WAh[rc] = make_uint2(packh2(wl0, wl1), packh2(wl2, wl3));
            PBh[rc] = packh2(b1l[rc], bias1[rc]);
        }
        if (t < 120) {
            int i = b * 120 + t;          // pair index: h = i/60, u = i%60
            int h = i / 60, u = i - h * 60;
            int c0 = h * C1 + u, c1 = c0 + 60;
            const float4 wl0 = ((const float4*)W2l)[c0], wl1 = ((const float4*)W2l)[c1];
            const float4 wr0 = ((const float4*)W2r)[c0], wr1 = ((const float4*)W2r)[c1];
            W2P[i*2]   = make_uint4(packh2(wl0.x, wl1.x), packh2(wl0.y, wl1.y),
                                    packh2(wl0.z, wl1.z), packh2(wl0.w, wl1.w));
            W2P[i*2+1] = make_uint4(packh2(wr0.x, wr1.x), packh2(wr0.y, wr1.y),
                                    packh2(wr0.z, wr1.z), packh2(wr0.w, wr1.w));
        }
        return;
    }
    __shared__ float Pp[3][72];
    __shared__ float Ps[72];
    {
        int o = t % 72, p = t / 72;
        if (t < 216) {
            int h = o / 9, j = o % 9;
            float acc = 0.f;
            int u0 = p * 40;
            for (int u = u0; u < u0 + 40; ++u) {
                int c = h * C1 + u;
                float a = att1[c];
                float w;
                if (j < 4)      w = W1l[j * F1 + c];
                else if (j < 8) w = W1r[(j - 4) * F1 + c];
                else            w = b1l[c] + b1r[c];
                acc = fmaf(a, w, acc);
            }
            Pp[p][o] = acc;
        }
    }
    __syncthreads();
    if (t < 72) Ps[t] = 0.6f * (Pp[0][t] + Pp[1][t] + Pp[2][t]);
    __syncthreads();
    int n = (b - 4) * 250 + t;
    if (t < 250) {
        float4 xv = ((const float4*)x)[n];
        xh[n] = make_uint2(packh2(xv.x, xv.y), packh2(xv.z, xv.w));
#pragma unroll
        for (int h = 0; h < H1; ++h) {
            const float* p = Ps + h * 9;
            Ls[n*8+h] = xv.x*p[0] + xv.y*p[1] + xv.z*p[2] + xv.w*p[3];
            Lr[n*8+h] = xv.x*p[4] + xv.y*p[5] + xv.z*p[6] + xv.w*p[7] + p[8];
        }
    }
}

// ---------------- layer-1 logits: LDS-staged 32x32x16 MFMA, bucket-ordered e1 ----------------
// 512-thread blocks (8 waves, 256 edges; 32 edges/wave). Bucket fill stores
// each edge's slot in LDS -> writeout scatters e1 to the bucket slot, so
// fused_agg1 reads e1 CONTIGUOUSLY.

__global__ __launch_bounds__(512) void logits_mfma(
        const int* __restrict__ ei, const uint2* __restrict__ xh,
        const uint4* __restrict__ BpH, const int* __restrict__ Bh,
        const float* __restrict__ Ls, const float* __restrict__ Lr,
        int* __restrict__ cnt, int* __restrict__ slist,
        float* __restrict__ e1) {
    __shared__ uint4 BpL[2048];   // 32 KB
    __shared__ int eposL[256];    // bucket slot per block-local edge
    int tid = threadIdx.x;
#pragma unroll
    for (int i = 0; i < 4; ++i) BpL[tid + i*512] = BpH[tid + i*512];
    // fused bucket fill (same 256 edges this block's waves compute)
    {
        int lidx = tid & 255;
        int ef = blockIdx.x * 256 + lidx;
        if (tid < 256 && ef < E_TOT) {
            int s, d;
            if (ef < N_EDGES) { s = ei[ef]; d = ei[N_EDGES + ef]; }
            else { s = ef - N_EDGES; d = s; }
            int pos = atomicAdd(&cnt[d], 1);
            int slot = d * BSTRIDE + pos;
            slist[slot] = s;
            eposL[lidx] = slot;
        }
    }
    __syncthreads();

    int ebase = blockIdx.x * 256 + (tid >> 6) * 32;
    if (ebase >= E_TOT) return;
    int lane = tid & 63;
    int ecol = lane & 31, g2 = lane >> 5;

    // gather: lanes<32 load edge (ebase+ecol); lanes>=32 carry the k8=1.0 row
    int s0 = 0, d0 = 0;
    AU zu;
    if (g2 == 0) {
        int er = ebase + ecol;
        if (er >= E_TOT) er = E_TOT - 1;
        if (er < N_EDGES) { s0 = ei[er]; d0 = ei[N_EDGES + er]; }
        else { s0 = er - N_EDGES; d0 = s0; }
        uint2 a = xh[s0], bb = xh[d0];
        zu.u = make_uint4(a.x, a.y, bb.x, bb.y);
    } else {
        zu.u = make_uint4(0x00003C00u, 0u, 0u, 0u);   // k8 = 1.0 (bias row)
    }
    int sA = __shfl(s0, ecol, 64), dA = __shfl(d0, ecol, 64);
    float4 lsv = *(const float4*)(Ls + sA*8 + 4*g2);
    float4 lrv = *(const float4*)(Lr + dA*8 + 4*g2);

    float kk0 = 0.f, kk1 = 0.f, kk2 = 0.f, kk3 = 0.f;
#pragma unroll
    for (int h = 0; h < H1; ++h) {
        int bh = Bh[h];
        float aa = 0.f;
#pragma unroll
        for (int tt = 0; tt < 4; ++tt) {
            int ct = h * 4 + tt;
            AU wu; wu.u = BpL[ct*64 + lane];
            f32x16 z = {0.f,0.f,0.f,0.f,0.f,0.f,0.f,0.f,0.f,0.f,0.f,0.f,0.f,0.f,0.f,0.f};
            f32x16 dd = __builtin_amdgcn_mfma_f32_32x32x16_f16(wu.h, zu.h, z, 0, 0, 0);
#pragma unroll
            for (int r = 0; r < 16; ++r) {
                int row = (r & 3) + 8 * (r >> 2) + 4 * g2;
                float sel = (tt*32 + row < bh) ? 1.f : -1.f;
                aa = fmaf(sel, fabsf(dd[r]), aa);
            }
        }
        aa += __shfl_xor(aa, 32, 64);   // combine complementary row halves
        bool pk = ((h >> 2) == g2);
        if ((h & 3) == 0)      kk0 = pk ? aa : kk0;
        else if ((h & 3) == 1) kk1 = pk ? aa : kk1;
        else if ((h & 3) == 2) kk2 = pk ? aa : kk2;
        else                   kk3 = pk ? aa : kk3;
    }

    // writeout to bucket slot (lane (ecol,g2) writes heads 4*g2..4*g2+3)
    {
        int e0 = ebase + ecol;
        if (e0 < E_TOT) {
            int slot = eposL[(tid >> 6) * 32 + ecol];
            float4 o = make_float4(__expf(lsv.x + lrv.x + kk0),
                                   __expf(lsv.y + lrv.y + kk1),
                                   __expf(lsv.z + lrv.z + kk2),
                                   __expf(lsv.w + lrv.w + kk3));
            *(float4*)(e1 + (size_t)slot*8 + 4*g2) = o;
        }
    }
}

// ---------------- layer-1 agg + f16 expand + relu + layer-2 transform ----------------
// 16 lanes per node; bucket CSR; e1 read CONTIGUOUSLY (bucket order)

#define AGG(hi, wv) { float W_ = (wv); ssum[hi] += W_; ag[hi].x += W_*xv.x; ag[hi].y += W_*xv.y; ag[hi].z += W_*xv.z; ag[hi].w += W_*xv.w; }

__global__ __launch_bounds__(256) void fused_agg1(
        const int* __restrict__ cnt, const int* __restrict__ slist,
        const float* __restrict__ e1, const float* __restrict__ x,
        const uint2* __restrict__ WAh, const unsigned* __restrict__ PBh,
        const uint4* __restrict__ W2P,
        const float* __restrict__ b2l, const float* __restrict__ b2r,
        float* __restrict__ xl2, float* __restrict__ xr2) {
    int tid = threadIdx.x;
    int node = blockIdx.x * 16 + (tid >> 4);
    int l = tid & 15;
    int beg = node * BSTRIDE, end = beg + cnt[node];

    float ssum[H1]; float4 ag[H1];
#pragma unroll
    for (int h = 0; h < H1; ++h) { ssum[h] = 0.f; ag[h] = make_float4(0.f,0.f,0.f,0.f); }

    for (int i = beg + l; i < end; i += 16) {
        const float4* p = (const float4*)(e1 + (size_t)i * 8);
        float4 wa = p[0], wb = p[1];
        float4 xv = ((const float4*)x)[slist[i]];
        AGG(0, wa.x) AGG(1, wa.y) AGG(2, wa.z) AGG(3, wa.w)
        AGG(4, wb.x) AGG(5, wb.y) AGG(6, wb.z) AGG(7, wb.w)
    }
#pragma unroll
    for (int off = 8; off; off >>= 1) {
#pragma unroll
        for (int h = 0; h < H1; ++h) {
            ssum[h] += __shfl_xor(ssum[h], off, 64);
            ag[h].x += __shfl_xor(ag[h].x, off, 64);
            ag[h].y += __shfl_xor(ag[h].y, off, 64);
            ag[h].z += __shfl_xor(ag[h].z, off, 64);
            ag[h].w += __shfl_xor(ag[h].w, off, 64);
        }
    }
    unsigned agA[H1], agB[H1], sg[H1];
#pragma unroll
    for (int h = 0; h < H1; ++h) {
        float inv = 1.f / (ssum[h] + 1e-16f);
        agA[h] = packh2(ag[h].x * inv, ag[h].y * inv);
        agB[h] = packh2(ag[h].z * inv, ag[h].w * inv);
        sg[h]  = packh2(ssum[h] * inv, 1.f);
    }

    float al0=0, al1=0, al2=0, al3=0, ar0=0, ar1=0, ar2=0, ar3=0;
#pragma unroll
    for (int h = 0; h < H1; ++h) {
        h2 ga = toh2(agA[h]), gb = toh2(agB[h]), gs = toh2(sg[h]);
#pragma unroll
        for (int j = 0; j < 4; ++j) {
            int u = l + 16*j;
            if (u < 60) {
                int c0 = h*C1 + u;
                uint2 wa0 = WAh[c0];      unsigned pb0 = PBh[c0];
                uint2 wa1 = WAh[c0 + 60]; unsigned pb1 = PBh[c0 + 60];
                float f0 = FDOT2(gs, toh2(pb0), 0.f);
                f0 = FDOT2(ga, toh2(wa0.x), f0);
                f0 = FDOT2(gb, toh2(wa0.y), f0);
                f0 = fmaxf(f0, 0.f);
                float f1 = FDOT2(gs, toh2(pb1), 0.f);
                f1 = FDOT2(ga, toh2(wa1.x), f1);
                f1 = FDOT2(gb, toh2(wa1.y), f1);
                f1 = fmaxf(f1, 0.f);
                h2 hp = toh2(packh2(f0, f1));
                int pi = (h*60 + u) * 2;
                uint4 wA = W2P[pi], wB = W2P[pi + 1];
                al0 = FDOT2(hp, toh2(wA.x), al0); al1 = FDOT2(hp, toh2(wA.y), al1);
                al2 = FDOT2(hp, toh2(wA.z), al2); al3 = FDOT2(hp, toh2(wA.w), al3);
                ar0 = FDOT2(hp, toh2(wB.x), ar0); ar1 = FDOT2(hp, toh2(wB.y), ar1);
                ar2 = FDOT2(hp, toh2(wB.z), ar2); ar3 = FDOT2(hp, toh2(wB.w), ar3);
            }
        }
    }
#pragma unroll
    for (int off = 8; off; off >>= 1) {
        al0 += __shfl_xor(al0, off, 64); al1 += __shfl_xor(al1, off, 64);
        al2 += __shfl_xor(al2, off, 64); al3 += __shfl_xor(al3, off, 64);
        ar0 += __shfl_xor(ar0, off, 64); ar1 += __shfl_xor(ar1, off, 64);
        ar2 += __shfl_xor(ar2, off, 64); ar3 += __shfl_xor(ar3, off, 64);
    }
    if (l == 0) {
        ((float4*)xl2)[node] = make_float4(al0 + b2l[0], al1 + b2l[1], al2 + b2l[2], al3 + b2l[3]);
        ((float4*)xr2)[node] = make_float4(ar0 + b2r[0], ar1 + b2r[1], ar2 + b2r[2], ar3 + b2r[3]);
    }
}

// ---------------- layer-2 fused attention ----------------

__global__ __launch_bounds__(256) void attn2(
        const int* __restrict__ cnt, const int* __restrict__ slist,
        const float* __restrict__ xl2, const float* __restrict__ xr2,
        const float* __restrict__ att2, const float* __restrict__ bias2,
        float* __restrict__ out) {
    int tid = threadIdx.x;
    int node = blockIdx.x * 16 + (tid >> 4);
    int l = tid & 15;
    int beg = node * BSTRIDE, end = beg + cnt[node];
    float4 xr = ((const float4*)xr2)[node];
    float a0 = att2[0], a1 = att2[1], a2 = att2[2], a3 = att2[3];

    float ssum = 0.f;
    float4 acc = make_float4(0.f, 0.f, 0.f, 0.f);
    for (int i = beg + l; i < end; i += 16) {
        float4 v = ((const float4*)xl2)[slist[i]];
        float lg = a0*lrelu(v.x + xr.x) + a1*lrelu(v.y + xr.y)
                 + a2*lrelu(v.z + xr.z) + a3*lrelu(v.w + xr.w);
        float w = __expf(lg);
        ssum += w;
        acc.x += w*v.x; acc.y += w*v.y; acc.z += w*v.z; acc.w += w*v.w;
    }
#pragma unroll
    for (int off = 8; off; off >>= 1) {
        ssum  += __shfl_xor(ssum,  off, 64);
        acc.x += __shfl_xor(acc.x, off, 64);
        acc.y += __shfl_xor(acc.y, off, 64);
        acc.z += __shfl_xor(acc.z, off, 64);
        acc.w += __shfl_xor(acc.w, off, 64);
    }
    if (l == 0) {
        float inv = 1.f / (ssum + 1e-16f);
        ((float4*)out)[node] = make_float4(acc.x*inv + bias2[0], acc.y*inv + bias2[1],
                                           acc.z*inv + bias2[2], acc.w*inv + bias2[3]);
    }
}

extern "C" void kernel_launch(void* const* d_in, const int* in_sizes, int n_in,
                              void* d_out, int out_size, void* d_ws, size_t ws_size,
                              hipStream_t stream) {
    const float* x     = (const float*)d_in[0];
    const int*   ei    = (const int*)  d_in[1];
    const float* W1l   = (const float*)d_in[2];
    const float* W1r   = (const float*)d_in[3];
    const float* b1l   = (const float*)d_in[4];
    const float* b1r   = (const float*)d_in[5];
    const float* att1  = (const float*)d_in[6];
    const float* bias1 = (const float*)d_in[7];
    const float* W2l   = (const float*)d_in[8];
    const float* W2r   = (const float*)d_in[9];
    const float* b2l   = (const float*)d_in[10];
    const float* b2r   = (const float*)d_in[11];
    const float* att2  = (const float*)d_in[12];
    const float* bias2 = (const float*)d_in[13];
    float* out = (float*)d_out;

    // workspace carve-up (segments 16B-aligned)
    float* e1   = (float*)d_ws;                   // N_NODES*BSTRIDE*8 = 5,120,000 f (BUCKET order)
    float* Ls   = e1 + (size_t)N_NODES * BSTRIDE * 8;  // 80,000
    float* Lr   = Ls + 80000;                     // 80,000
    float* xl2  = Lr + 80000;                     // 40,000
    float* xr2  = xl2 + 40000;                    // 40,000
    unsigned* BpHu = (unsigned*)(xr2 + 40000);    // 8,192 (uint4[2048])
    int* Bh     = (int*)(BpHu + 8192);            // 16 (8 used)
    unsigned* WAhu = (unsigned*)(Bh + 16);        // 1,920 (uint2[960])
    unsigned* W2Pu = WAhu + 1920;                 // 7,680 (uint4[1920])
    unsigned* PBhu = W2Pu + 7680;                 // 960
    unsigned* xhu  = PBhu + 960;                  // 20,000 (uint2[10000])
    int* cnt    = (int*)(xhu + 20000);            // 10,000
    int* slist  = cnt + 10000;                    // N_NODES*BSTRIDE = 640,000

    const int B = 256;

    prep<<<84, B, 0, stream>>>(
        x, W1l, W1r, b1l, b1r, att1, bias1, W2l, W2r,
        (uint4*)BpHu, Bh, (uint2*)WAhu, PBhu, (uint4*)W2Pu,
        (uint2*)xhu, Ls, Lr, cnt);

    logits_mfma<<<(E_TOT + 255) / 256, 512, 0, stream>>>(
        ei, (const uint2*)xhu, (const uint4*)BpHu, Bh, Ls, Lr,
        cnt, slist, e1);
    fused_agg1<<<N_NODES / 16, B, 0, stream>>>(
        cnt, slist, e1, x, (const uint2*)WAhu, PBhu, (const uint4*)W2Pu,
        b2l, b2r, xl2, xr2);
    attn2<<<N_NODES / 16, B, 0, stream>>>(cnt, slist, xl2, xr2, att2, bias2, out);
}